// Round 6
// baseline (128.272 us; speedup 1.0000x reference)
//
#include <hip/hip_runtime.h>
#include <math.h>

// Tropical (max-plus) depthwise conv2d, 5x5, stride 1, pad 2, dilation 1.
// x: (8,32,224,224) f32, kernel: (32,1,5,5) f32, out: (8,32,224,224) f32.
// out[b,c,h,w] = max_{i,j} x[b,c,h-2+i, w-2+j] + kernel[c,0,4-i,4-j]
//
// R12: register sliding-window streaming, scatter form. No LDS, no barriers.
// R11's counters showed the kernel is LATENCY-bound (VALUBusy 30%, HBM 19%,
// occ 33%): the stage->vmcnt(0)->compute structure serializes. Here each
// lane owns a 4-col strip, streams 28 output rows top-to-bottom:
//  - 5-slot register ring u[5][8] of input-row windows, prefetch distance 3
//    (3 rows x 3 loads in flight; compiler emits counted vmcnt(N) waits --
//    the async pattern it preserves, unlike LDS staging).
//  - scatter: input row g updates the 5 pending output accumulators
//    acc[(g+2-i)%5] with weight row i; row g-2 completes and is NT-stored.
//  - all ring indices compile-time (inner loop unrolled by 5; outer
//    #pragma unroll 1 keeps code ~7KB, I-cache resident).
// Per input row: 1x(f2,f4,f2) load (32B), ~156 VALU (max3-fused), 1 store
// per completed row. Row redundancy 32/28 = 1.14 (vs R6 1.25, R7 2.0).
// Grid: 2048 one-wave blocks (8/CU); XCD-chunked swizzle (2048%8==0).

#define TC_B 8
#define TC_C 32
#define TC_H 224
#define TC_W 224
#define TC_WQ 56              // f4 per image row
#define HS 28                 // output rows per strip
#define NSTRIP (TC_H / HS)    // 8
#define NWG (TC_B * TC_C * NSTRIP)  // 2048
#define NXCD 8
#define WPX (NWG / NXCD)      // 256, exact

typedef float f4v __attribute__((ext_vector_type(4)));  // NT-store-legal

// Load one input-row window into 8 regs: cols [4l-2, 4l+6) of row ga.
// OOB rows and OOB edge columns become -inf (tropical neutral).
__device__ __forceinline__ void load_row(float* us, const float* __restrict__ xp,
                                         int ga, int col0, bool ledge, bool redge) {
  const float NEG = -INFINITY;
  if (ga >= 0 && ga < TC_H) {              // wave-uniform branch
    const float* rp = xp + (size_t)ga * TC_W + col0;
    const float2 A2 = ledge ? make_float2(NEG, NEG) : *(const float2*)(rp - 2);
    const float4 B4 = *(const float4*)(rp);
    const float2 C2 = redge ? make_float2(NEG, NEG) : *(const float2*)(rp + 4);
    us[0] = A2.x; us[1] = A2.y; us[2] = B4.x; us[3] = B4.y;
    us[4] = B4.z; us[5] = B4.w; us[6] = C2.x; us[7] = C2.y;
  } else {
    #pragma unroll
    for (int m = 0; m < 8; ++m) us[m] = NEG;
  }
}

// Fold weight-row w5 of input window uu into accumulator row a[4].
// BIRTH: overwrite (first contribution, i=0). Else max-accumulate.
// max3-friendly nesting: 5 adds + 3 max-insts (2 for birth) per output.
template <bool BIRTH>
__device__ __forceinline__ void upd_row(float* a, const float* uu,
                                        const float* w5) {
  #pragma unroll
  for (int k = 0; k < 4; ++k) {
    const float t0 = uu[k + 0] + w5[0];
    const float t1 = uu[k + 1] + w5[1];
    const float t2 = uu[k + 2] + w5[2];
    const float t3 = uu[k + 3] + w5[3];
    const float t4 = uu[k + 4] + w5[4];
    const float xm = fmaxf(fmaxf(t0, t1), t2);               // v_max3
    const float ym = BIRTH ? fmaxf(t3, t4)
                           : fmaxf(fmaxf(t3, t4), a[k]);     // v_max3
    a[k] = fmaxf(xm, ym);
  }
}

__global__ __launch_bounds__(64) void tropical_conv2d_kernel(
    const float* __restrict__ x, const float* __restrict__ kern,
    float* __restrict__ out) {
  const int lane = threadIdx.x;     // one wave per block

  // XCD-chunked swizzle: each XCD owns contiguous logical tiles (strips of
  // the same plane share halo rows + weights in its L2).
  const int orig = blockIdx.x;
  const int blk = (orig & (NXCD - 1)) * WPX + (orig >> 3);

  const int strip = blk & (NSTRIP - 1);
  const int bc = blk >> 3;          // b*C + c (uniform)
  const int c = bc & (TC_C - 1);

  // weights: w[i*5+j] = wflip[i][j] = kern[c][4-i][4-j]; c uniform.
  float w[25];
  #pragma unroll
  for (int q = 0; q < 25; ++q) w[q] = kern[c * 25 + 24 - q];

  if (lane >= TC_WQ) return;        // 56 data lanes; no LDS/barrier -> legal

  const bool ledge = (lane == 0);
  const bool redge = (lane == TC_WQ - 1);
  const int col0 = lane * 4;
  const float* xp = x + (size_t)bc * (TC_H * TC_W);
  const int r0 = strip * HS;

  const float NEG = -INFINITY;
  float u[5][8];                    // input-row window ring, row r in slot r%5
  float acc[5][4];                  // pending output rows, row r in slot r%5
  #pragma unroll
  for (int s = 0; s < 5; ++s)
    #pragma unroll
    for (int k = 0; k < 4; ++k) acc[s][k] = NEG;

  // ---- prologue: issue rows -2..2 (slots 3,4,0,1,2) -> 15 loads in flight
  load_row(u[3], xp, r0 - 2, col0, ledge, redge);
  load_row(u[4], xp, r0 - 1, col0, ledge, redge);
  load_row(u[0], xp, r0 + 0, col0, ledge, redge);
  load_row(u[1], xp, r0 + 1, col0, ledge, redge);
  load_row(u[2], xp, r0 + 2, col0, ledge, redge);

  // g=-2: births out row 0 (i=0). g=-1: i=1 into row 0, births row 1.
  upd_row<true >(acc[0], u[3], &w[0]);
  upd_row<false>(acc[0], u[4], &w[5]);
  upd_row<true >(acc[1], u[4], &w[0]);

  float* opb = out + (size_t)bc * (TC_H * TC_W) + (size_t)r0 * TC_W + col0;

  // ---- steady: input rows g = 0..29 (consume slot g%5, prefetch g+3) ----
  #pragma unroll 1
  for (int t = 0; t < 6; ++t) {
    #pragma unroll
    for (int q = 0; q < 5; ++q) {          // q = g % 5 (compile-time)
      const int g = 5 * t + q;
      // prefetch row g+3 into slot (q+3)%5 (its old row g-2 dies this iter);
      // skip unneeded rows 30,31,32 (uniform branch).
      if (g < 27) load_row(u[(q + 3) % 5], xp, r0 + g + 3, col0, ledge, redge);

      // scatter row g into pending outputs r = g-2..g+2 (weight row i=g-r+2)
      upd_row<false>(acc[(q + 3) % 5], u[q], &w[20]);  // i=4, r=g-2 (completes)
      upd_row<false>(acc[(q + 4) % 5], u[q], &w[15]);  // i=3, r=g-1
      upd_row<false>(acc[q],           u[q], &w[10]);  // i=2, r=g
      upd_row<false>(acc[(q + 1) % 5], u[q], &w[5]);   // i=1, r=g+1

      // store completed out row r=g-2 (valid iff g>=2; uniform on t for q<2)
      if (q >= 2 || t > 0) {
        const float* a = acc[(q + 3) % 5];
        f4v val = {a[0], a[1], a[2], a[3]};
        __builtin_nontemporal_store(val, (f4v*)(opb + (size_t)(g - 2) * TC_W));
      }

      upd_row<true>(acc[(q + 2) % 5], u[q], &w[0]);    // i=0, births r=g+2
    }
  }
}

extern "C" void kernel_launch(void* const* d_in, const int* in_sizes, int n_in,
                              void* d_out, int out_size, void* d_ws, size_t ws_size,
                              hipStream_t stream) {
  const float* x = (const float*)d_in[0];
  const float* k = (const float*)d_in[1];
  float* out = (float*)d_out;

  dim3 block(64, 1, 1);
  dim3 grid(NWG, 1, 1);
  tropical_conv2d_kernel<<<grid, block, 0, stream>>>(x, k, out);
}

// Round 7
// 110.431 us; speedup vs baseline: 1.1616x; 1.1616x over previous
//
#include <hip/hip_runtime.h>
#include <math.h>

// Tropical (max-plus) depthwise conv2d, 5x5, stride 1, pad 2, dilation 1.
// x: (8,32,224,224) f32, kernel: (32,1,5,5) f32, out: (8,32,224,224) f32.
// out[b,c,h,w] = max_{i,j} x[b,c,h-2+i, w-2+j] + kernel[c,0,4-i,4-j]
//
// R13 = exact revert to R6 (best measured: dur 110.3, conv ~27us) with ONE
// strictly-dominant tweak: the 25 taps touch only cols 4l-2..4l+5 (32B),
// so read f2@rp+2 + f4@rp+4 + f2@rp+8 instead of 3x f4 (48B). Same 3 DS
// instructions, -33% LDS read traffic, -4 VGPRs. Session evidence:
//  - R7 direct-load (no LDS): +5us (halo re-read, per-row branch).
//  - R11 split-stage 2-phase: +20us (compiler drains vmcnt(0) at barrier;
//    2-pass doubles ds_reads) -- counters: VALUBusy 30%, HBM 19%, occ 33%.
//  - R12 register streaming, 1 wave/blk: +18us (occupancy 15%, VALU 36%).
//  - R9/R10 (swizzle, max3, NT stores, 32-row tile): all within +-2us noise.
// Conclusion: 7-blocks/CU inter-block overlap with one barrier is the
// local optimum; intra-block pipelining attempts all lost to it.

#define TC_B 8
#define TC_C 32
#define TC_H 224
#define TC_W 224
#define TC_WQ 56          // f4 per image row
#define TC_HG 14          // 224/16 row-groups
#define T_ROWS 20         // 16 data + 2+2 halo rows
#define ROW_F4 65         // LDS row stride in float4
#define ROW_FL (ROW_F4 * 4)

__global__ __launch_bounds__(256) void tropical_conv2d_kernel(
    const float* __restrict__ x, const float* __restrict__ kern,
    float* __restrict__ out) {
  const int tid = threadIdx.x;
  const int lane = tid & 63;
  const int yl = tid >> 6;          // wave 0..3
  const int blk = blockIdx.x;
  const int hg = blk % TC_HG;
  const int bc = blk / TC_HG;       // b*C + c (uniform)
  const int c = bc & (TC_C - 1);

  __shared__ float tile[T_ROWS * ROW_FL];   // 20*65*16 = 20800 B

  const float NEG = -INFINITY;
  const float4 NINF4 = make_float4(NEG, NEG, NEG, NEG);
  const float* xp = x + (size_t)bc * (TC_H * TC_W);

  // left-halo f4 (index 0) of every row = -inf; staging never writes f4 0.
  if (tid < T_ROWS) *(float4*)&tile[tid * ROW_FL] = NINF4;

  // ---- staging: wave yl owns tile rows yl*5 .. yl*5+4 ----
  const int cl = lane < TC_WQ ? lane : TC_WQ - 1;   // clamp spill lanes
  #pragma unroll
  for (int rr = 0; rr < 5; ++rr) {
    const int r = yl * 5 + rr;                      // wave-uniform
    const int g = hg * 16 - 2 + r;                  // global row, uniform
    float* ldsrow = &tile[r * ROW_FL + 4];          // f4 index 1 (uniform base)
    if (g >= 0 && g < TC_H) {
      const float* gp = xp + (size_t)g * TC_W + cl * 4;
      // lane i -> LDS f4 index 1+i, holding x f4 col min(i,55)
      __builtin_amdgcn_global_load_lds(
          (const __attribute__((address_space(1))) void*)gp,
          (__attribute__((address_space(3))) void*)ldsrow, 16, 0, 0);
    } else {
      *(float4*)(ldsrow + (size_t)lane * 4) = NINF4;  // OOB row = -inf
    }
  }

  // weights while staging flies: c uniform -> scalar loads
  // w[i*5+j] = wflip[i][j] = kern[c][4-i][4-j]
  float w[25];
  #pragma unroll
  for (int q = 0; q < 25; ++q) w[q] = kern[c * 25 + 24 - q];

  __syncthreads();   // drains vmcnt (global_load_lds) + lgkmcnt

  if (lane >= TC_WQ) return;

  const int hbase = hg * 16 + yl * 4;   // first of this thread's 4 output rows

  float acc[4][4];
  #pragma unroll
  for (int o = 0; o < 4; ++o)
    #pragma unroll
    for (int k = 0; k < 4; ++k) acc[o][k] = NEG;

  const bool redge = (lane == TC_WQ - 1);

  // tile row (yl*4 + ri) holds input row hbase-2+ri
  #pragma unroll
  for (int ri = 0; ri < 8; ++ri) {
    const float* rp = &tile[(yl * 4 + ri) * ROW_FL + 4 * lane];
    // Window u[0..7] = cols 4l-2 .. 4l+5 (exactly the taps; 32B not 48B).
    // lane 0: rp+2 lands in f4 index 0 = -inf halo (set above).
    const float2 A2 = *(const float2*)(rp + 2);   // cols 4l-2, 4l-1
    const float4 B4 = *(const float4*)(rp + 4);   // cols 4l .. 4l+3
    const float2 C2 = *(const float2*)(rp + 8);   // cols 4l+4, 4l+5
    float u[8] = {A2.x, A2.y, B4.x, B4.y, B4.z, B4.w, C2.x, C2.y};
    // right edge: f4 57 holds lane-spill garbage -> mask cols 224,225
    u[6] = redge ? NEG : u[6];
    u[7] = redge ? NEG : u[7];

    #pragma unroll
    for (int o = 0; o < 4; ++o) {
      const int i = ri - o;                // weight row (compile-time)
      if (i < 0 || i > 4) continue;
      #pragma unroll
      for (int k = 0; k < 4; ++k) {
        const float t0 = u[k + 0] + w[i * 5 + 0];
        const float t1 = u[k + 1] + w[i * 5 + 1];
        const float t2 = u[k + 2] + w[i * 5 + 2];
        const float t3 = u[k + 3] + w[i * 5 + 3];
        const float t4 = u[k + 4] + w[i * 5 + 4];
        acc[o][k] = fmaxf(fmaxf(fmaxf(acc[o][k], t0), t1),
                          fmaxf(fmaxf(t2, t3), t4));
      }
    }
  }

  float* op = out + (size_t)bc * (TC_H * TC_W) + (size_t)hbase * TC_W;
  #pragma unroll
  for (int o = 0; o < 4; ++o) {
    ((float4*)(op + (size_t)o * TC_W))[lane] =
        make_float4(acc[o][0], acc[o][1], acc[o][2], acc[o][3]);
  }
}

extern "C" void kernel_launch(void* const* d_in, const int* in_sizes, int n_in,
                              void* d_out, int out_size, void* d_ws, size_t ws_size,
                              hipStream_t stream) {
  const float* x = (const float*)d_in[0];
  const float* k = (const float*)d_in[1];
  float* out = (float*)d_out;

  dim3 block(256, 1, 1);
  dim3 grid(TC_B * TC_C * TC_HG, 1, 1);
  tropical_conv2d_kernel<<<grid, block, 0, stream>>>(x, k, out);
}